// Round 3
// baseline (327.303 us; speedup 1.0000x reference)
//
#include <hip/hip_runtime.h>
#include <math.h>

// Log2 quantization (n_bits=4, per-channel symmetric) of x[4096][11008] fp32.
// out = sign(x) * 2^clamp(rint(log2(|x|+eps)), zero, zero+7), 0 if below range,
// zero = floor(log2(max_row|x| + eps) + 0.5) - 7.
//
// R2: same as R1 but with clang ext_vector_type for the nontemporal store
// (HIP_vector_type float4 is a class — rejected by the builtin).

#define NROW 4096
#define D    11008
#define D4   (D / 4)       // 2752, exact
#define EPSF 1e-32f
#define NTHREADS 256

typedef float floatx4 __attribute__((ext_vector_type(4)));

__device__ __forceinline__ float quant_one(float v, float zero) {
    float a  = fabsf(v);
    float xl = log2f(a + EPSF);          // matches numpy log2 (absmax 0 in R0)
    float xi = rintf(xl);                // round half-even == jnp.round
    float c1 = fmaxf(xi - zero, -1.0f);  // x_c1
    float c  = fminf(c1 - 8.0f, -1.0f);  // x_c (half_levels = 8)
    float q  = exp2f(c + 8.0f + zero);   // exact: integer-valued exponent
    if (c1 <= -1.0f) q = 0.0f;           // zero flag
    return copysignf(q, v);              // sign(x); q==0 when x==0
}

__global__ __launch_bounds__(NTHREADS)
void log2_quant_kernel(const float* __restrict__ x, float* __restrict__ out) {
    __shared__ float wmax[NTHREADS / 64];

    const int r   = blockIdx.x;
    const int tid = threadIdx.x;
    const floatx4* __restrict__ xr = (const floatx4*)(x + (size_t)r * D);
    floatx4* __restrict__ outr     = (floatx4*)(out + (size_t)r * D);

    // Phase 1: streaming read, per-thread max |x| (no LDS copy).
    float m = 0.0f;
    for (int i = tid; i < D4; i += NTHREADS) {
        floatx4 v = xr[i];
        m = fmaxf(m, fmaxf(fmaxf(fabsf(v.x), fabsf(v.y)),
                           fmaxf(fabsf(v.z), fabsf(v.w))));
    }

    // Wave-level max reduce (64 lanes), then cross-wave via 16 B LDS.
    #pragma unroll
    for (int off = 32; off > 0; off >>= 1)
        m = fmaxf(m, __shfl_down(m, off, 64));

    const int lane = tid & 63;
    const int wid  = tid >> 6;
    if (lane == 0) wmax[wid] = m;
    __syncthreads();

    const float xmax    = fmaxf(fmaxf(wmax[0], wmax[1]), fmaxf(wmax[2], wmax[3]));
    const float max_val = floorf(log2f(xmax + EPSF) + 0.5f);
    const float zero    = max_val - 7.0f;

    // Phase 2: re-read the row (L2/LLC-hot), quantize, nontemporal store.
    for (int i = tid; i < D4; i += NTHREADS) {
        floatx4 v = xr[i];
        floatx4 o;
        o.x = quant_one(v.x, zero);
        o.y = quant_one(v.y, zero);
        o.z = quant_one(v.z, zero);
        o.w = quant_one(v.w, zero);
        __builtin_nontemporal_store(o, &outr[i]);
    }
}

extern "C" void kernel_launch(void* const* d_in, const int* in_sizes, int n_in,
                              void* d_out, int out_size, void* d_ws, size_t ws_size,
                              hipStream_t stream) {
    const float* x = (const float*)d_in[0];
    float* out     = (float*)d_out;
    // n_bits (d_in[1]) fixed at 4 per setup_inputs(); hard-coded above.
    log2_quant_kernel<<<NROW, NTHREADS, 0, stream>>>(x, out);
}

// Round 5
// 321.032 us; speedup vs baseline: 1.0195x; 1.0195x over previous
//
#include <hip/hip_runtime.h>
#include <math.h>

// Log2 quantization (n_bits=4, per-channel symmetric) of x[4096][11008] fp32.
// out = sign(x) * 2^clamp(rint(log2(|x|+eps)), zero, zero+7), 0 if below range,
// zero = floor(log2(max_row|x| + eps) + 0.5) - 7.
//
// R4 == R3 (GPU acquisition timed out; no data). Split into two streaming
// kernels:
//   A: per-row |max| reduce -> zero[row] in d_ws (pure read, 180 MB)
//   B: elementwise quantize  (read 180 MB — LLC-hot from A — write 176 MB, NT)
// R2's single-kernel read->barrier->write structure sat at 2.9 TB/s despite
// minimal HBM traffic; pure streams without in-block phase coupling hit ~6 TB/s.

#define NROW 4096
#define D    11008
#define D4   (D / 4)       // 2752 = 10*256 + 192
#define EPSF 1e-32f
#define NTHREADS 256
#define NTILES 11          // ceil(D4 / NTHREADS)

typedef float floatx4 __attribute__((ext_vector_type(4)));

__device__ __forceinline__ float quant_one(float v, float zero) {
    float a  = fabsf(v);
    float xl = log2f(a + EPSF);          // matches numpy log2 (absmax 0 R0/R2)
    float xi = rintf(xl);                // round half-even == jnp.round
    float c1 = fmaxf(xi - zero, -1.0f);  // x_c1
    float c  = fminf(c1 - 8.0f, -1.0f);  // x_c (half_levels = 8)
    float q  = exp2f(c + 8.0f + zero);   // exact: integer-valued exponent
    if (c1 <= -1.0f) q = 0.0f;           // zero flag
    return copysignf(q, v);              // sign(x); q==0 when x==0
}

// Kernel A: one block per row, pure streaming read + max reduce.
__global__ __launch_bounds__(NTHREADS)
void rowzero_kernel(const float* __restrict__ x, float* __restrict__ zeros) {
    __shared__ float wmax[NTHREADS / 64];

    const int r   = blockIdx.x;
    const int tid = threadIdx.x;
    const floatx4* __restrict__ xr = (const floatx4*)(x + (size_t)r * D);

    float m0 = 0.0f, m1 = 0.0f;
    int i = tid;
    // 2752 = 5 * 512 + 192: unrolled-by-2 main loop, then tail.
    #pragma unroll
    for (int k = 0; k < 5; ++k, i += 2 * NTHREADS) {
        floatx4 a = xr[i];
        floatx4 b = xr[i + NTHREADS];
        m0 = fmaxf(m0, fmaxf(fmaxf(fabsf(a.x), fabsf(a.y)),
                             fmaxf(fabsf(a.z), fabsf(a.w))));
        m1 = fmaxf(m1, fmaxf(fmaxf(fabsf(b.x), fabsf(b.y)),
                             fmaxf(fabsf(b.z), fabsf(b.w))));
    }
    if (i < D4) {                        // tail: 192 lanes
        floatx4 a = xr[i];
        m0 = fmaxf(m0, fmaxf(fmaxf(fabsf(a.x), fabsf(a.y)),
                             fmaxf(fabsf(a.z), fabsf(a.w))));
    }
    float m = fmaxf(m0, m1);

    #pragma unroll
    for (int off = 32; off > 0; off >>= 1)
        m = fmaxf(m, __shfl_down(m, off, 64));

    if ((tid & 63) == 0) wmax[tid >> 6] = m;
    __syncthreads();

    if (tid == 0) {
        float xmax = fmaxf(fmaxf(wmax[0], wmax[1]), fmaxf(wmax[2], wmax[3]));
        zeros[r] = floorf(log2f(xmax + EPSF) + 0.5f) - 7.0f;
    }
}

// Kernel B: pure elementwise quantize. grid = (NTILES, NROW).
__global__ __launch_bounds__(NTHREADS)
void quant_kernel(const float* __restrict__ x, const float* __restrict__ zeros,
                  float* __restrict__ out) {
    const int r = blockIdx.y;
    const int i = blockIdx.x * NTHREADS + threadIdx.x;
    if (i >= D4) return;

    const float zero = zeros[r];         // block-uniform -> scalar load
    const floatx4* __restrict__ xr = (const floatx4*)(x + (size_t)r * D);
    floatx4* __restrict__ outr     = (floatx4*)(out + (size_t)r * D);

    floatx4 v = xr[i];
    floatx4 o;
    o.x = quant_one(v.x, zero);
    o.y = quant_one(v.y, zero);
    o.z = quant_one(v.z, zero);
    o.w = quant_one(v.w, zero);
    __builtin_nontemporal_store(o, &outr[i]);
}

extern "C" void kernel_launch(void* const* d_in, const int* in_sizes, int n_in,
                              void* d_out, int out_size, void* d_ws, size_t ws_size,
                              hipStream_t stream) {
    const float* x = (const float*)d_in[0];
    float* out     = (float*)d_out;
    float* zeros   = (float*)d_ws;       // 4096 floats = 16 KB scratch
    // n_bits (d_in[1]) fixed at 4 per setup_inputs(); hard-coded above.
    rowzero_kernel<<<NROW, NTHREADS, 0, stream>>>(x, zeros);
    quant_kernel<<<dim3(NTILES, NROW), NTHREADS, 0, stream>>>(x, zeros, out);
}